// Round 11
// baseline (497.036 us; speedup 1.0000x reference)
//
#include <hip/hip_runtime.h>
#include <stdint.h>

// Problem constants
//  SEQ=1024 (32x32), BSZ=8, EMBED=1024, KD=64, NDIM=16, V=64, R=16384, R2=16
//  DIRS=4, H=64, CDIM=4096
//
// DIAGNOSTIC ROUND 3: REP=8 amplification (bijective rotation, idempotent)
// on k_pre/k_w/k_kd/k_t2; k_conv REP=1 (already characterized at ~23us, R7)
// so it cannot flood the top-5. Amplified durations = 8x true cost.

#define REP 8

typedef __attribute__((ext_vector_type(8))) short short8;   // 8 bf16 (4 VGPRs)
typedef __attribute__((ext_vector_type(4))) float f32x4;    // MFMA accumulator

__device__ inline uint16_t f2bf(float f) {   // fp32 -> bf16 RNE
    uint32_t u = __float_as_uint(f);
    uint32_t r = (u + 0x7FFFu + ((u >> 16) & 1u)) >> 16;
    return (uint16_t)r;
}
__device__ inline float bf2f(uint16_t v) {
    return __uint_as_float((uint32_t)v << 16);
}
__device__ inline uint32_t packbf(float a, float b) {
    return (uint32_t)f2bf(a) | ((uint32_t)f2bf(b) << 16);
}

// ---------------------------------------------------------------------------
// K_pre: transpose/pack half tiles + one-shot tables. REP-amplified.
// ---------------------------------------------------------------------------
__global__ __launch_bounds__(256) void k_pre(const float* __restrict__ x,
                                             uint16_t* __restrict__ xtb,
                                             const float* __restrict__ A,
                                             const float* __restrict__ B1,
                                             const float* __restrict__ B2,
                                             float* __restrict__ LAg,
                                             float* __restrict__ SBg) {
    __shared__ __align__(16) float shf[32 * 129];   // [e_local][r_local], 16.5 KB
    int t = threadIdx.x;

    for (int rep = 0; rep < REP; ++rep) {
        int bx = (blockIdx.x + rep * 257) % 2054;   // bijective rotation
        if (bx < 2048) {
            int u = bx & 31, e0 = ((bx >> 5) & 31) * 32, r0 = (bx >> 10) * 128;
            {
                int c = t & 7, a = t >> 3;
                const float* src = x + (size_t)(u * 256 + r0) * 1024 + e0 + c * 4;
                #pragma unroll
                for (int qq = 0; qq < 4; ++qq) {
                    int r = qq * 32 + a;
                    float4 v = *(const float4*)(src + (size_t)r * 1024);
                    shf[(c * 4 + 0) * 129 + r] = v.x;
                    shf[(c * 4 + 1) * 129 + r] = v.y;
                    shf[(c * 4 + 2) * 129 + r] = v.z;
                    shf[(c * 4 + 3) * 129 + r] = v.w;
                }
            }
            __syncthreads();
            {
                int e_local = t >> 3, b = t & 7;
                const float* row = shf + e_local * 129;
                int v0 = r0 >> 3;
                uint32_t pk[8];
                #pragma unroll
                for (int k2 = 0; k2 < 8; ++k2)
                    pk[k2] = packbf(row[(2 * k2) * 8 + b], row[(2 * k2 + 1) * 8 + b]);
                uint16_t* dst = xtb + (size_t)(e0 + e_local) * 8192 + u * 256 + b * 32 + v0;
                *(uint4*)dst       = make_uint4(pk[0], pk[1], pk[2], pk[3]);
                *(uint4*)(dst + 8) = make_uint4(pk[4], pk[5], pk[6], pk[7]);
            }
        } else {
            int i = bx - 2048;                          // 0..5
            int e = t * 4;
            if (i < 4) {
                float4 v = *(const float4*)(A + i * 1024 + e);
                float4 o;
                o.x = -log2f(1.0f + expf(-v.x));
                o.y = -log2f(1.0f + expf(-v.y));
                o.z = -log2f(1.0f + expf(-v.z));
                o.w = -log2f(1.0f + expf(-v.w));
                *(float4*)(LAg + i * 1024 + e) = o;
            } else {
                const float* Bs = (i == 4) ? B1 : B2;
                float4 v = *(const float4*)(Bs + e);
                float4 o;
                o.x = 1.0f / (1.0f + expf(-v.x));
                o.y = 1.0f / (1.0f + expf(-v.y));
                o.z = 1.0f / (1.0f + expf(-v.z));
                o.w = 1.0f / (1.0f + expf(-v.w));
                *(float4*)(SBg + (i - 4) * 1024 + e) = o;
            }
        }
        __syncthreads();
        asm volatile("" ::: "memory");
    }
}

// ---------------------------------------------------------------------------
// K_w: fused selector-GEMV + w compute. REP-amplified.
// ---------------------------------------------------------------------------
__global__ __launch_bounds__(256) void k_w(const float* __restrict__ om,
                                           const float* __restrict__ LAg,
                                           const float* __restrict__ SBg,
                                           float* __restrict__ w) {
    __shared__ float ff[2][16][4];    // selector indices as floats
    __shared__ float cf[2][16][2];    // B-row cols 0,1
    int t = threadIdx.x;

    for (int rep = 0; rep < REP; ++rep) {
        int p = (blockIdx.x + rep * 101) & 1023;    // bijective rotation
        {
            int row_id = t >> 1, h = t & 1;
            int d = row_id >> 6, a = (row_id >> 4) & 3, r2 = row_id & 15;
            const float* src = om + ((size_t)(d * 5 + a) * 16384 + p * 16 + r2) * 64 + h * 32;
            float s = 0.0f;
            #pragma unroll
            for (int q = 0; q < 8; ++q) {
                float4 v = *(const float4*)(src + q * 4);
                float jb = (float)(h * 32 + q * 4);
                s = __builtin_fmaf(v.x, jb,
                    __builtin_fmaf(v.y, jb + 1.0f,
                    __builtin_fmaf(v.z, jb + 2.0f,
                    __builtin_fmaf(v.w, jb + 3.0f, s))));
            }
            s += __shfl_xor(s, 1);
            if (h == 0) ff[d][r2][a] = s;
            if (t < 32) {
                int dd = t >> 4, rr = t & 15;
                const float* c = om + ((size_t)(dd * 5 + 4) * 16384 + p * 16 + rr) * 64;
                cf[dd][rr][0] = c[0];
                cf[dd][rr][1] = c[1];
            }
        }
        __syncthreads();

        int d = t >> 7;                            // wave-uniform
        int j0 = (t & 127) * 8;
        float L0[8], L1[8], L2[8], L3[8], B0v[8], B1v[8], acc[8];
        #pragma unroll
        for (int a = 0; a < 4; ++a) {
            float* La = (a == 0) ? L0 : (a == 1) ? L1 : (a == 2) ? L2 : L3;
            float4 u0 = *(const float4*)(LAg + a * 1024 + j0);
            float4 u1 = *(const float4*)(LAg + a * 1024 + j0 + 4);
            La[0] = u0.x; La[1] = u0.y; La[2] = u0.z; La[3] = u0.w;
            La[4] = u1.x; La[5] = u1.y; La[6] = u1.z; La[7] = u1.w;
        }
        {
            float4 u0 = *(const float4*)(SBg + j0);
            float4 u1 = *(const float4*)(SBg + j0 + 4);
            float4 v0 = *(const float4*)(SBg + 1024 + j0);
            float4 v1 = *(const float4*)(SBg + 1024 + j0 + 4);
            B0v[0] = u0.x; B0v[1] = u0.y; B0v[2] = u0.z; B0v[3] = u0.w;
            B0v[4] = u1.x; B0v[5] = u1.y; B0v[6] = u1.z; B0v[7] = u1.w;
            B1v[0] = v0.x; B1v[1] = v0.y; B1v[2] = v0.z; B1v[3] = v0.w;
            B1v[4] = v1.x; B1v[5] = v1.y; B1v[6] = v1.z; B1v[7] = v1.w;
        }
        #pragma unroll
        for (int jj = 0; jj < 8; ++jj) acc[jj] = 0.0f;

        #pragma unroll
        for (int r2 = 0; r2 < 16; ++r2) {
            float f0 = ff[d][r2][0];
            float f1 = ff[d][r2][1];
            float f2 = ff[d][r2][2];
            float f3 = ff[d][r2][3];
            float c0 = cf[d][r2][0];
            float c1 = cf[d][r2][1];
            #pragma unroll
            for (int jj = 0; jj < 8; ++jj) {
                float ex = __builtin_fmaf(f3, L3[jj],
                           __builtin_fmaf(f2, L2[jj],
                           __builtin_fmaf(f1, L1[jj], f0 * L0[jj])));
                float bs = __builtin_fmaf(c1, B1v[jj], c0 * B0v[jj]);
                acc[jj] = __builtin_fmaf(exp2f(ex), bs, acc[jj]);
            }
        }
        float* dst = w + (size_t)(d * 1024 + p) * 1024 + j0;
        *(float4*)(dst)     = make_float4(acc[0], acc[1], acc[2], acc[3]);
        *(float4*)(dst + 4) = make_float4(acc[4], acc[5], acc[6], acc[7]);
        __syncthreads();
        asm volatile("" ::: "memory");
    }
}

// ---------------------------------------------------------------------------
// K_kd: kd4b[dir][e][p] (bf16). REP-amplified.
// ---------------------------------------------------------------------------
__global__ __launch_bounds__(256) void k_kd(const float* __restrict__ w,
                                            const float* __restrict__ C1,
                                            const float* __restrict__ C2,
                                            uint16_t* __restrict__ kd4b) {
    __shared__ float Wl[128 * 33];
    __shared__ float Ctl[32 * 65];
    int t = threadIdx.x;

    for (int rep = 0; rep < REP; ++rep) {
        int kap = (blockIdx.x + rep * 13) & 63;     // bijective rotation
        int p0 = blockIdx.y * 128;
        int dir = kap >> 4, m = kap & 15;
        {
            int off = (t & 3) * 4;
            #pragma unroll
            for (int rr = 0; rr < 4; ++rr) {
                int row_id = rr * 64 + (t >> 2);
                int d = row_id >> 7, pp = row_id & 127;
                const float* src = w + ((size_t)(d * 1024 + p0 + pp) * 64 + kap) * 16 + off;
                float4 v = *(const float4*)src;
                float* dstl = Wl + pp * 33 + d * 16 + off;
                dstl[0] = v.x; dstl[1] = v.y; dstl[2] = v.z; dstl[3] = v.w;
            }
        }
        if (t < 128) {
            int d = t >> 6, h = t & 63;
            const float* Cd = d ? C2 : C1;
            const float* src = Cd + (size_t)(h * 64 + kap) * 16;
            #pragma unroll
            for (int q = 0; q < 16; ++q)
                Ctl[(d * 16 + q) * 65 + h] = src[q] * 0.25f;
        }
        __syncthreads();

        int ph = t & 15, hq = t >> 4;
        int pl = ph * 8, h0 = hq * 4;
        float acc[8][4];
        #pragma unroll
        for (int i = 0; i < 8; ++i)
            { acc[i][0] = acc[i][1] = acc[i][2] = acc[i][3] = 0.0f; }

        for (int k = 0; k < 32; ++k) {
            float c0 = Ctl[k * 65 + h0 + 0];
            float c1 = Ctl[k * 65 + h0 + 1];
            float c2 = Ctl[k * 65 + h0 + 2];
            float c3 = Ctl[k * 65 + h0 + 3];
            #pragma unroll
            for (int i = 0; i < 8; ++i) {
                float wv = Wl[(pl + i) * 33 + k];
                acc[i][0] += wv * c0; acc[i][1] += wv * c1;
                acc[i][2] += wv * c2; acc[i][3] += wv * c3;
            }
        }
        #pragma unroll
        for (int j = 0; j < 4; ++j) {
            int h = h0 + j;
            uint32_t pk[4];
            #pragma unroll
            for (int qq = 0; qq < 4; ++qq) {
                float v0, v1;
                #pragma unroll
                for (int z = 0; z < 2; ++z) {
                    int p = p0 + pl + qq * 2 + z;
                    int ii = p >> 5, jj = p & 31;
                    float f = ((ii == 0) != (jj == 0)) ? 2.0f : 1.0f;
                    float val = acc[qq * 2 + z][j] * f;
                    if (z == 0) v0 = val; else v1 = val;
                }
                pk[qq] = packbf(v0, v1);
            }
            uint16_t* dst = kd4b + ((size_t)(dir * 1024 + h * 16 + m)) * 1024 + p0 + pl;
            *(uint4*)dst = make_uint4(pk[0], pk[1], pk[2], pk[3]);
        }
        __syncthreads();
        asm volatile("" ::: "memory");
    }
}

// ---------------------------------------------------------------------------
// K_conv (MFMA): row-pair packed + static schedule (R10 best). NOT amplified.
// ---------------------------------------------------------------------------
__global__ __launch_bounds__(256) void k_conv(const uint16_t* __restrict__ xtb,
                                              const uint16_t* __restrict__ kd4b,
                                              uint16_t* __restrict__ ytb) {
    __shared__ __align__(16) char smem[24576 + 16384];  // Krev + Xt
    const int KROW = 768;   // 8 s-rows * 96 B
    const int SROW = 96;    // 48 shorts per s-row, no pad
    char* xtl = smem + 24576;

    int e = blockIdx.x;
    int t = threadIdx.x;
    int lane = t & 63, wv = t >> 6;
    int n = lane & 15, q = lane >> 4, nn = n & 7, hi = n >> 3;

    {
        f32x4 z = {0.f, 0.f, 0.f, 0.f};
        #pragma unroll
        for (int k = 0; k < 6; ++k)
            *(f32x4*)(smem + (t + k * 256) * 16) = z;
    }
    {
        const uint4* src = (const uint4*)(xtb + (size_t)e * 8192);
        #pragma unroll
        for (int r = 0; r < 4; ++r) {
            uint4 v = src[r * 256 + t];
            *(uint4*)(xtl + (r * 256 + t) * 16) = v;
        }
    }
    int pi = t >> 3, pj = (t & 7) * 4;
    float s0, s1, s2, s3;
    {
        const uint16_t* b0 = kd4b + (size_t)e * 1024;
        ushort4 a0 = *(const ushort4*)(b0 + pi * 32 + pj);
        ushort4 a1 = *(const ushort4*)(b0 + (1 << 20) + (31 - pi) * 32 + pj);
        ushort4 a2 = *(const ushort4*)(b0 + (2 << 20) + pi * 32 + (28 - pj));
        ushort4 a3 = *(const ushort4*)(b0 + (3 << 20) + (31 - pi) * 32 + (28 - pj));
        s0 = bf2f(a0.x) + bf2f(a1.x) + bf2f(a2.w) + bf2f(a3.w);
        s1 = bf2f(a0.y) + bf2f(a1.y) + bf2f(a2.z) + bf2f(a3.z);
        s2 = bf2f(a0.z) + bf2f(a1.z) + bf2f(a2.y) + bf2f(a3.y);
        s3 = bf2f(a0.w) + bf2f(a1.w) + bf2f(a2.x) + bf2f(a3.x);
    }
    __syncthreads();

    {
        uint16_t k0 = f2bf(s0), k1 = f2bf(s1), k2 = f2bf(s2), k3 = f2bf(s3);
        #pragma unroll
        for (int s = 0; s < 8; ++s) {
            uint16_t* row = (uint16_t*)(smem + pi * KROW + s * SROW);
            int c = 31 + s - pj;
            row[c]     = k0;
            row[c - 1] = k1;
            row[c - 2] = k2;
            row[c - 3] = k3;
        }
    }
    __syncthreads();

    int A0 = n - 8 * q;
    int A1 = A0 + 16;
    int sh1 = (A1 + 9) & 7;
    int off1 = sh1 * SROW + (31 + sh1 - A1) * 2;
    int off0;
    if (A0 >= -8) {
        int sh0 = (A0 + 9) & 7;
        off0 = sh0 * SROW + (31 + sh0 - A0) * 2;
    } else {
        off0 = 80;
    }
    int boff = nn * 64 + q * 16;
    const char* zptr = smem + 80;

    f32x4 acc0[4], acc1[4];
    #pragma unroll
    for (int ii = 0; ii < 4; ++ii) {
        acc0[ii] = (f32x4){0.f, 0.f, 0.f, 0.f};
        acc1[ii] = (f32x4){0.f, 0.f, 0.f, 0.f};
    }

    #pragma unroll
    for (int j = 0; j < 8; ++j) {
        if (j <= 2 * wv + 1) {
            const char* krow = smem + j * KROW;
            short8 a0 = *(const short8*)(krow + off0);
            short8 a1 = *(const short8*)(krow + off1);
            {
                int u = 2 * wv + hi - j;
                const char* bp = (u >= 0) ? (xtl + u * 512 + boff) : zptr;
                short8 bb = *(const short8*)bp;
                acc0[0] = __builtin_amdgcn_mfma_f32_16x16x32_bf16(a0, bb, acc0[0], 0, 0, 0);
                acc1[0] = __builtin_amdgcn_mfma_f32_16x16x32_bf16(a1, bb, acc1[0], 0, 0, 0);
            }
            #pragma unroll
            for (int ii = 1; ii < 4; ++ii) {
                int u = 2 * wv + 8 * ii + hi - j;
                short8 bb = *(const short8*)(xtl + u * 512 + boff);
                acc0[ii] = __builtin_amdgcn_mfma_f32_16x16x32_bf16(a0, bb, acc0[ii], 0, 0, 0);
                acc1[ii] = __builtin_amdgcn_mfma_f32_16x16x32_bf16(a1, bb, acc1[ii], 0, 0, 0);
            }
        }
    }
    #pragma unroll
    for (int b = 1; b <= 3; ++b) {
        #pragma unroll
        for (int m = 0; m < 8; ++m) {
            int di = 2 * wv + 8 * b - 6 + m;
            const char* krow = smem + di * KROW;
            short8 a0 = *(const short8*)(krow + off0);
            short8 a1 = *(const short8*)(krow + off1);
            #pragma unroll
            for (int ii = b; ii < 4; ++ii) {
                int u = 8 * (ii - b) + 6 + hi - m;
                const char* bp = ((ii == b) && (m == 7) && (hi == 0))
                                     ? zptr : (xtl + u * 512 + boff);
                short8 bb = *(const short8*)bp;
                acc0[ii] = __builtin_amdgcn_mfma_f32_16x16x32_bf16(a0, bb, acc0[ii], 0, 0, 0);
                acc1[ii] = __builtin_amdgcn_mfma_f32_16x16x32_bf16(a1, bb, acc1[ii], 0, 0, 0);
            }
        }
    }

    {
        uint16_t* base = ytb + ((size_t)(nn * 1024 + e)) * 1024 + q * 4;
        #pragma unroll
        for (int ii = 0; ii < 4; ++ii) {
            int ro = 2 * wv + 8 * ii + hi;
            uint2 w0 = make_uint2(packbf(acc0[ii][0], acc0[ii][1]),
                                  packbf(acc0[ii][2], acc0[ii][3]));
            uint2 w1 = make_uint2(packbf(acc1[ii][0], acc1[ii][1]),
                                  packbf(acc1[ii][2], acc1[ii][3]));
            *(uint2*)(base + ro * 32)      = w0;
            *(uint2*)(base + ro * 32 + 16) = w1;
        }
    }
}

// ---------------------------------------------------------------------------
// K_t2: out[p][b][e] = ytb[b][e][p] + x[p][b][e]*omega[e]. REP-amplified.
// ---------------------------------------------------------------------------
__global__ __launch_bounds__(256) void k_t2(const uint16_t* __restrict__ ytb,
                                            const float* __restrict__ x,
                                            const float* __restrict__ omega,
                                            float* __restrict__ out) {
    __shared__ float lds[32 * 130];   // [e][pl], pad 130 (8B-aligned float2)
    int t = threadIdx.x;

    for (int rep = 0; rep < REP; ++rep) {
        int e0 = ((blockIdx.x + rep * 5) & 31) * 32;    // bijective rotation
        int p0 = blockIdx.y * 128, b = blockIdx.z;
        {
            int a = t >> 3, c = t & 7;
            const uint16_t* src = ytb + (size_t)(b * 1024 + e0 + a) * 1024 + p0;
            float* dst = lds + a * 130;
            #pragma unroll
            for (int rr = 0; rr < 2; ++rr) {
                int off = (c + rr * 8) * 8;
                uint4 v = *(const uint4*)(src + off);
                uint32_t ww[4] = {v.x, v.y, v.z, v.w};
                #pragma unroll
                for (int k = 0; k < 4; ++k) {
                    float2 f;
                    f.x = bf2f((uint16_t)(ww[k] & 0xFFFFu));
                    f.y = bf2f((uint16_t)(ww[k] >> 16));
                    *(float2*)(dst + off + k * 2) = f;
                }
            }
        }
        __syncthreads();
        int pl = t >> 1, eh = (t & 1) * 16;
        int p = p0 + pl;
        const float* xs = x + ((size_t)(p * 8 + b)) * 1024 + e0 + eh;
        float* os = out + ((size_t)(p * 8 + b)) * 1024 + e0 + eh;
        #pragma unroll
        for (int qq = 0; qq < 4; ++qq) {
            float4 xv = *(const float4*)(xs + qq * 4);
            int eb = eh + qq * 4;
            float4 ov;
            ov.x = lds[(eb + 0) * 130 + pl] + xv.x * omega[e0 + eb + 0];
            ov.y = lds[(eb + 1) * 130 + pl] + xv.y * omega[e0 + eb + 1];
            ov.z = lds[(eb + 2) * 130 + pl] + xv.z * omega[e0 + eb + 2];
            ov.w = lds[(eb + 3) * 130 + pl] + xv.w * omega[e0 + eb + 3];
            *(float4*)(os + qq * 4) = ov;
        }
        __syncthreads();
        asm volatile("" ::: "memory");
    }
}

// ---------------------------------------------------------------------------
extern "C" void kernel_launch(void* const* d_in, const int* in_sizes, int n_in,
                              void* d_out, int out_size, void* d_ws, size_t ws_size,
                              hipStream_t stream) {
    (void)in_sizes; (void)n_in; (void)out_size; (void)ws_size;
    const float* x   = (const float*)d_in[0];
    const float* A   = (const float*)d_in[1];
    const float* B1  = (const float*)d_in[2];
    const float* B2  = (const float*)d_in[3];
    const float* C1  = (const float*)d_in[4];
    const float* C2  = (const float*)d_in[5];
    const float* omg = (const float*)d_in[6];
    const float* om  = (const float*)d_in[7];
    float* out = (float*)d_out;

    float* ws  = (float*)d_ws;
    uint16_t* xtb  = (uint16_t*)ws;                     // 16 MB
    uint16_t* kd4b = (uint16_t*)(ws + 4194304);         // 8 MB
    uint16_t* ytb  = (uint16_t*)(ws + 6291456);         // 16 MB
    float* w       = ws + 10485760;                     // 8 MB
    float* LAg     = ws + 4194304 + 65536;              // 16 KB  [4][1024]
    float* SBg     = ws + 4194304 + 69632;              // 8 KB   [2][1024]

    k_pre <<<2054, 256, 0, stream>>>(x, xtb, A, B1, B2, LAg, SBg);
    k_w   <<<1024, 256, 0, stream>>>(om, LAg, SBg, w);
    k_kd  <<<dim3(64, 8), 256, 0, stream>>>(w, C1, C2, kd4b);
    k_conv<<<1024, 256, 0, stream>>>(xtb, kd4b, ytb);
    k_t2  <<<dim3(32, 8, 8), 256, 0, stream>>>(ytb, x, omg, out);
}

// Round 12
// 184.740 us; speedup vs baseline: 2.6905x; 2.6905x over previous
//
#include <hip/hip_runtime.h>
#include <stdint.h>

// Problem constants
//  SEQ=1024 (32x32), BSZ=8, EMBED=1024, KD=64, NDIM=16, V=64, R=16384, R2=16
//  DIRS=4, H=64, CDIM=4096

typedef __attribute__((ext_vector_type(8))) short short8;   // 8 bf16 (4 VGPRs)
typedef __attribute__((ext_vector_type(4))) float f32x4;    // MFMA accumulator

__device__ inline uint16_t f2bf(float f) {   // fp32 -> bf16 RNE
    uint32_t u = __float_as_uint(f);
    uint32_t r = (u + 0x7FFFu + ((u >> 16) & 1u)) >> 16;
    return (uint16_t)r;
}
__device__ inline float bf2f(uint16_t v) {
    return __uint_as_float((uint32_t)v << 16);
}
__device__ inline uint32_t packbf(float a, float b) {
    return (uint32_t)f2bf(a) | ((uint32_t)f2bf(b) << 16);
}

// ---------------------------------------------------------------------------
// K_pre (R5 form): 2054 blocks.
//   bx in [0,2048): transpose/pack half tiles (32 e x 128 r), LDS 16.5 KB.
//   bx in [2048,2054): one-shot tables LAg = -log2(sigmoid(A)), SBg = sigmoid(B).
// ---------------------------------------------------------------------------
__global__ __launch_bounds__(256) void k_pre(const float* __restrict__ x,
                                             uint16_t* __restrict__ xtb,
                                             const float* __restrict__ A,
                                             const float* __restrict__ B1,
                                             const float* __restrict__ B2,
                                             float* __restrict__ LAg,
                                             float* __restrict__ SBg) {
    __shared__ __align__(16) float shf[32 * 129];   // [e_local][r_local], 16.5 KB
    int bx = blockIdx.x;
    int t = threadIdx.x;

    if (bx < 2048) {
        int u = bx & 31, e0 = ((bx >> 5) & 31) * 32, r0 = (bx >> 10) * 128;
        {
            int c = t & 7, a = t >> 3;          // c: e-chunk lane, a: row 0..31
            const float* src = x + (size_t)(u * 256 + r0) * 1024 + e0 + c * 4;
            #pragma unroll
            for (int qq = 0; qq < 4; ++qq) {
                int r = qq * 32 + a;
                float4 v = *(const float4*)(src + (size_t)r * 1024);
                shf[(c * 4 + 0) * 129 + r] = v.x;
                shf[(c * 4 + 1) * 129 + r] = v.y;
                shf[(c * 4 + 2) * 129 + r] = v.z;
                shf[(c * 4 + 3) * 129 + r] = v.w;
            }
        }
        __syncthreads();
        {
            int e_local = t >> 3, b = t & 7;
            const float* row = shf + e_local * 129;
            int v0 = r0 >> 3;                   // 0 or 16
            uint32_t pk[8];
            #pragma unroll
            for (int k2 = 0; k2 < 8; ++k2)
                pk[k2] = packbf(row[(2 * k2) * 8 + b], row[(2 * k2 + 1) * 8 + b]);
            uint16_t* dst = xtb + (size_t)(e0 + e_local) * 8192 + u * 256 + b * 32 + v0;
            *(uint4*)dst       = make_uint4(pk[0], pk[1], pk[2], pk[3]);
            *(uint4*)(dst + 8) = make_uint4(pk[4], pk[5], pk[6], pk[7]);
        }
    } else {
        int i = bx - 2048;                          // 0..5
        int e = t * 4;
        if (i < 4) {
            float4 v = *(const float4*)(A + i * 1024 + e);
            float4 o;
            o.x = -log2f(1.0f + expf(-v.x));
            o.y = -log2f(1.0f + expf(-v.y));
            o.z = -log2f(1.0f + expf(-v.z));
            o.w = -log2f(1.0f + expf(-v.w));
            *(float4*)(LAg + i * 1024 + e) = o;
        } else {
            const float* Bs = (i == 4) ? B1 : B2;
            float4 v = *(const float4*)(Bs + e);
            float4 o;
            o.x = 1.0f / (1.0f + expf(-v.x));
            o.y = 1.0f / (1.0f + expf(-v.y));
            o.z = 1.0f / (1.0f + expf(-v.z));
            o.w = 1.0f / (1.0f + expf(-v.w));
            *(float4*)(SBg + (i - 4) * 1024 + e) = o;
        }
    }
}

// ---------------------------------------------------------------------------
// K_w (R12): one block per (d,p) — 2048 blocks, 2x parallelism vs R5.
//   GEMV: 4 threads/row (4-deep chain, 2x shfl_xor reduce) over this d's
//   64 one-hot rows; selector sum is EXACT (one-hot x small ints).
//   Main: 4 jj/thread (tables 24 VGPR, acc 4) -> ~60 VGPR, high occupancy.
//   Bitwise-identical w output vs R5 (same per-element op order).
// ---------------------------------------------------------------------------
__global__ __launch_bounds__(256) void k_w(const float* __restrict__ om,
                                           const float* __restrict__ LAg,
                                           const float* __restrict__ SBg,
                                           float* __restrict__ w) {
    __shared__ float ffl[16][4];      // selector indices as floats (this d)
    __shared__ float cfl[16][2];      // B-row cols 0,1 (this d)
    int bx = blockIdx.x;
    int d = bx >> 10, p = bx & 1023;
    int t = threadIdx.x;
    {
        int row_id = t >> 2, h = t & 3;               // 64 rows x 4 quarters
        int a = row_id >> 4, r2 = row_id & 15;
        const float* src = om + ((size_t)(d * 5 + a) * 16384 + p * 16 + r2) * 64 + h * 16;
        float s = 0.0f;
        #pragma unroll
        for (int q = 0; q < 4; ++q) {
            float4 v = *(const float4*)(src + q * 4);
            float jb = (float)(h * 16 + q * 4);
            s = __builtin_fmaf(v.x, jb,
                __builtin_fmaf(v.y, jb + 1.0f,
                __builtin_fmaf(v.z, jb + 2.0f,
                __builtin_fmaf(v.w, jb + 3.0f, s))));
        }
        s += __shfl_xor(s, 1);
        s += __shfl_xor(s, 2);
        if (h == 0) ffl[r2][a] = s;
        if (t < 16) {
            const float* c = om + ((size_t)(d * 5 + 4) * 16384 + p * 16 + t) * 64;
            cfl[t][0] = c[0];
            cfl[t][1] = c[1];
        }
    }
    __syncthreads();

    int j0 = t * 4;
    float L0[4], L1[4], L2[4], L3[4], B0v[4], B1v[4], acc[4];
    #pragma unroll
    for (int a = 0; a < 4; ++a) {
        float* La = (a == 0) ? L0 : (a == 1) ? L1 : (a == 2) ? L2 : L3;
        float4 u0 = *(const float4*)(LAg + a * 1024 + j0);
        La[0] = u0.x; La[1] = u0.y; La[2] = u0.z; La[3] = u0.w;
    }
    {
        float4 u0 = *(const float4*)(SBg + j0);
        float4 v0 = *(const float4*)(SBg + 1024 + j0);
        B0v[0] = u0.x; B0v[1] = u0.y; B0v[2] = u0.z; B0v[3] = u0.w;
        B1v[0] = v0.x; B1v[1] = v0.y; B1v[2] = v0.z; B1v[3] = v0.w;
    }
    #pragma unroll
    for (int jj = 0; jj < 4; ++jj) acc[jj] = 0.0f;

    #pragma unroll
    for (int r2 = 0; r2 < 16; ++r2) {
        float f0 = ffl[r2][0];
        float f1 = ffl[r2][1];
        float f2 = ffl[r2][2];
        float f3 = ffl[r2][3];
        float c0 = cfl[r2][0];
        float c1 = cfl[r2][1];
        #pragma unroll
        for (int jj = 0; jj < 4; ++jj) {
            float ex = __builtin_fmaf(f3, L3[jj],
                       __builtin_fmaf(f2, L2[jj],
                       __builtin_fmaf(f1, L1[jj], f0 * L0[jj])));
            float bs = __builtin_fmaf(c1, B1v[jj], c0 * B0v[jj]);
            acc[jj] = __builtin_fmaf(exp2f(ex), bs, acc[jj]);
        }
    }
    float* dst = w + (size_t)(d * 1024 + p) * 1024 + j0;
    *(float4*)dst = make_float4(acc[0], acc[1], acc[2], acc[3]);
}

// ---------------------------------------------------------------------------
// K_kd: kd4b[dir][e][p] (bf16) = boundary(p) * sum_{d,n} w*C/4
// ---------------------------------------------------------------------------
__global__ __launch_bounds__(256) void k_kd(const float* __restrict__ w,
                                            const float* __restrict__ C1,
                                            const float* __restrict__ C2,
                                            uint16_t* __restrict__ kd4b) {
    __shared__ float Wl[128 * 33];
    __shared__ float Ctl[32 * 65];
    int kap = blockIdx.x;
    int p0 = blockIdx.y * 128;
    int dir = kap >> 4, m = kap & 15;
    int t = threadIdx.x;

    {
        int off = (t & 3) * 4;
        #pragma unroll
        for (int rep = 0; rep < 4; ++rep) {
            int row_id = rep * 64 + (t >> 2);   // 0..255 = 2 d x 128 p
            int d = row_id >> 7, pp = row_id & 127;
            const float* src = w + ((size_t)(d * 1024 + p0 + pp) * 64 + kap) * 16 + off;
            float4 v = *(const float4*)src;
            float* dstl = Wl + pp * 33 + d * 16 + off;
            dstl[0] = v.x; dstl[1] = v.y; dstl[2] = v.z; dstl[3] = v.w;
        }
    }
    if (t < 128) {
        int d = t >> 6, h = t & 63;
        const float* Cd = d ? C2 : C1;
        const float* src = Cd + (size_t)(h * 64 + kap) * 16;
        #pragma unroll
        for (int q = 0; q < 16; ++q)
            Ctl[(d * 16 + q) * 65 + h] = src[q] * 0.25f;
    }
    __syncthreads();

    int ph = t & 15, hq = t >> 4;
    int pl = ph * 8, h0 = hq * 4;
    float acc[8][4];
    #pragma unroll
    for (int i = 0; i < 8; ++i)
        { acc[i][0] = acc[i][1] = acc[i][2] = acc[i][3] = 0.0f; }

    for (int k = 0; k < 32; ++k) {
        float c0 = Ctl[k * 65 + h0 + 0];
        float c1 = Ctl[k * 65 + h0 + 1];
        float c2 = Ctl[k * 65 + h0 + 2];
        float c3 = Ctl[k * 65 + h0 + 3];
        #pragma unroll
        for (int i = 0; i < 8; ++i) {
            float wv = Wl[(pl + i) * 33 + k];
            acc[i][0] += wv * c0; acc[i][1] += wv * c1;
            acc[i][2] += wv * c2; acc[i][3] += wv * c3;
        }
    }
    #pragma unroll
    for (int j = 0; j < 4; ++j) {
        int h = h0 + j;
        uint32_t pk[4];
        #pragma unroll
        for (int qq = 0; qq < 4; ++qq) {
            float v0, v1;
            #pragma unroll
            for (int z = 0; z < 2; ++z) {
                int p = p0 + pl + qq * 2 + z;
                int ii = p >> 5, jj = p & 31;
                float f = ((ii == 0) != (jj == 0)) ? 2.0f : 1.0f;
                float val = acc[qq * 2 + z][j] * f;
                if (z == 0) v0 = val; else v1 = val;
            }
            pk[qq] = packbf(v0, v1);
        }
        uint16_t* dst = kd4b + ((size_t)(dir * 1024 + h * 16 + m)) * 1024 + p0 + pl;
        *(uint4*)dst = make_uint4(pk[0], pk[1], pk[2], pk[3]);
    }
}

// ---------------------------------------------------------------------------
// K_conv (MFMA): row-pair packed + static schedule (R10 best, 187.5us).
// ---------------------------------------------------------------------------
__global__ __launch_bounds__(256) void k_conv(const uint16_t* __restrict__ xtb,
                                              const uint16_t* __restrict__ kd4b,
                                              uint16_t* __restrict__ ytb) {
    __shared__ __align__(16) char smem[24576 + 16384];  // Krev + Xt
    const int KROW = 768;   // 8 s-rows * 96 B
    const int SROW = 96;    // 48 shorts per s-row, no pad
    char* xtl = smem + 24576;

    int e = blockIdx.x;
    int t = threadIdx.x;
    int lane = t & 63, wv = t >> 6;
    int n = lane & 15, q = lane >> 4, nn = n & 7, hi = n >> 3;

    {
        f32x4 z = {0.f, 0.f, 0.f, 0.f};
        #pragma unroll
        for (int k = 0; k < 6; ++k)
            *(f32x4*)(smem + (t + k * 256) * 16) = z;
    }
    {
        const uint4* src = (const uint4*)(xtb + (size_t)e * 8192);
        #pragma unroll
        for (int r = 0; r < 4; ++r) {
            uint4 v = src[r * 256 + t];
            *(uint4*)(xtl + (r * 256 + t) * 16) = v;
        }
    }
    int pi = t >> 3, pj = (t & 7) * 4;
    float s0, s1, s2, s3;
    {
        const uint16_t* b0 = kd4b + (size_t)e * 1024;
        ushort4 a0 = *(const ushort4*)(b0 + pi * 32 + pj);
        ushort4 a1 = *(const ushort4*)(b0 + (1 << 20) + (31 - pi) * 32 + pj);
        ushort4 a2 = *(const ushort4*)(b0 + (2 << 20) + pi * 32 + (28 - pj));
        ushort4 a3 = *(const ushort4*)(b0 + (3 << 20) + (31 - pi) * 32 + (28 - pj));
        s0 = bf2f(a0.x) + bf2f(a1.x) + bf2f(a2.w) + bf2f(a3.w);
        s1 = bf2f(a0.y) + bf2f(a1.y) + bf2f(a2.z) + bf2f(a3.z);
        s2 = bf2f(a0.z) + bf2f(a1.z) + bf2f(a2.y) + bf2f(a3.y);
        s3 = bf2f(a0.w) + bf2f(a1.w) + bf2f(a2.x) + bf2f(a3.x);
    }
    __syncthreads();

    {
        uint16_t k0 = f2bf(s0), k1 = f2bf(s1), k2 = f2bf(s2), k3 = f2bf(s3);
        #pragma unroll
        for (int s = 0; s < 8; ++s) {
            uint16_t* row = (uint16_t*)(smem + pi * KROW + s * SROW);
            int c = 31 + s - pj;
            row[c]     = k0;
            row[c - 1] = k1;
            row[c - 2] = k2;
            row[c - 3] = k3;
        }
    }
    __syncthreads();

    int A0 = n - 8 * q;
    int A1 = A0 + 16;
    int sh1 = (A1 + 9) & 7;
    int off1 = sh1 * SROW + (31 + sh1 - A1) * 2;
    int off0;
    if (A0 >= -8) {
        int sh0 = (A0 + 9) & 7;
        off0 = sh0 * SROW + (31 + sh0 - A0) * 2;
    } else {
        off0 = 80;
    }
    int boff = nn * 64 + q * 16;
    const char* zptr = smem + 80;

    f32x4 acc0[4], acc1[4];
    #pragma unroll
    for (int ii = 0; ii < 4; ++ii) {
        acc0[ii] = (f32x4){0.f, 0.f, 0.f, 0.f};
        acc1[ii] = (f32x4){0.f, 0.f, 0.f, 0.f};
    }

    #pragma unroll
    for (int j = 0; j < 8; ++j) {
        if (j <= 2 * wv + 1) {
            const char* krow = smem + j * KROW;
            short8 a0 = *(const short8*)(krow + off0);
            short8 a1 = *(const short8*)(krow + off1);
            {
                int u = 2 * wv + hi - j;
                const char* bp = (u >= 0) ? (xtl + u * 512 + boff) : zptr;
                short8 bb = *(const short8*)bp;
                acc0[0] = __builtin_amdgcn_mfma_f32_16x16x32_bf16(a0, bb, acc0[0], 0, 0, 0);
                acc1[0] = __builtin_amdgcn_mfma_f32_16x16x32_bf16(a1, bb, acc1[0], 0, 0, 0);
            }
            #pragma unroll
            for (int ii = 1; ii < 4; ++ii) {
                int u = 2 * wv + 8 * ii + hi - j;
                short8 bb = *(const short8*)(xtl + u * 512 + boff);
                acc0[ii] = __builtin_amdgcn_mfma_f32_16x16x32_bf16(a0, bb, acc0[ii], 0, 0, 0);
                acc1[ii] = __builtin_amdgcn_mfma_f32_16x16x32_bf16(a1, bb, acc1[ii], 0, 0, 0);
            }
        }
    }
    #pragma unroll
    for (int b = 1; b <= 3; ++b) {
        #pragma unroll
        for (int m = 0; m < 8; ++m) {
            int di = 2 * wv + 8 * b - 6 + m;
            const char* krow = smem + di * KROW;
            short8 a0 = *(const short8*)(krow + off0);
            short8 a1 = *(const short8*)(krow + off1);
            #pragma unroll
            for (int ii = b; ii < 4; ++ii) {
                int u = 8 * (ii - b) + 6 + hi - m;
                const char* bp = ((ii == b) && (m == 7) && (hi == 0))
                                     ? zptr : (xtl + u * 512 + boff);
                short8 bb = *(const short8*)bp;
                acc0[ii] = __builtin_amdgcn_mfma_f32_16x16x32_bf16(a0, bb, acc0[ii], 0, 0, 0);
                acc1[ii] = __builtin_amdgcn_mfma_f32_16x16x32_bf16(a1, bb, acc1[ii], 0, 0, 0);
            }
        }
    }

    {
        uint16_t* base = ytb + ((size_t)(nn * 1024 + e)) * 1024 + q * 4;
        #pragma unroll
        for (int ii = 0; ii < 4; ++ii) {
            int ro = 2 * wv + 8 * ii + hi;
            uint2 w0 = make_uint2(packbf(acc0[ii][0], acc0[ii][1]),
                                  packbf(acc0[ii][2], acc0[ii][3]));
            uint2 w1 = make_uint2(packbf(acc1[ii][0], acc1[ii][1]),
                                  packbf(acc1[ii][2], acc1[ii][3]));
            *(uint2*)(base + ro * 32)      = w0;
            *(uint2*)(base + ro * 32 + 16) = w1;
        }
    }
}

// ---------------------------------------------------------------------------
// K_t2: out[p][b][e] = ytb[b][e][p] + x[p][b][e]*omega[e]
// ---------------------------------------------------------------------------
__global__ __launch_bounds__(256) void k_t2(const uint16_t* __restrict__ ytb,
                                            const float* __restrict__ x,
                                            const float* __restrict__ omega,
                                            float* __restrict__ out) {
    __shared__ float lds[32 * 130];   // [e][pl], pad 130 (8B-aligned float2)
    int e0 = blockIdx.x * 32, p0 = blockIdx.y * 128, b = blockIdx.z;
    int t = threadIdx.x;
    {
        int a = t >> 3, c = t & 7;          // a: e-row 0..31, c: 128B chunk
        const uint16_t* src = ytb + (size_t)(b * 1024 + e0 + a) * 1024 + p0;
        float* dst = lds + a * 130;
        #pragma unroll
        for (int rep = 0; rep < 2; ++rep) {
            int off = (c + rep * 8) * 8;    // p offset, 8 p per uint4
            uint4 v = *(const uint4*)(src + off);
            uint32_t ww[4] = {v.x, v.y, v.z, v.w};
            #pragma unroll
            for (int k = 0; k < 4; ++k) {
                float2 f;
                f.x = bf2f((uint16_t)(ww[k] & 0xFFFFu));
                f.y = bf2f((uint16_t)(ww[k] >> 16));
                *(float2*)(dst + off + k * 2) = f;
            }
        }
    }
    __syncthreads();
    int pl = t >> 1, eh = (t & 1) * 16;
    int p = p0 + pl;
    const float* xs = x + ((size_t)(p * 8 + b)) * 1024 + e0 + eh;
    float* os = out + ((size_t)(p * 8 + b)) * 1024 + e0 + eh;
    #pragma unroll
    for (int qq = 0; qq < 4; ++qq) {
        float4 xv = *(const float4*)(xs + qq * 4);
        int eb = eh + qq * 4;
        float4 ov;
        ov.x = lds[(eb + 0) * 130 + pl] + xv.x * omega[e0 + eb + 0];
        ov.y = lds[(eb + 1) * 130 + pl] + xv.y * omega[e0 + eb + 1];
        ov.z = lds[(eb + 2) * 130 + pl] + xv.z * omega[e0 + eb + 2];
        ov.w = lds[(eb + 3) * 130 + pl] + xv.w * omega[e0 + eb + 3];
        *(float4*)(os + qq * 4) = ov;
    }
}

// ---------------------------------------------------------------------------
extern "C" void kernel_launch(void* const* d_in, const int* in_sizes, int n_in,
                              void* d_out, int out_size, void* d_ws, size_t ws_size,
                              hipStream_t stream) {
    (void)in_sizes; (void)n_in; (void)out_size; (void)ws_size;
    const float* x   = (const float*)d_in[0];
    const float* A   = (const float*)d_in[1];
    const float* B1  = (const float*)d_in[2];
    const float* B2  = (const float*)d_in[3];
    const float* C1  = (const float*)d_in[4];
    const float* C2  = (const float*)d_in[5];
    const float* omg = (const float*)d_in[6];
    const float* om  = (const float*)d_in[7];
    float* out = (float*)d_out;

    float* ws  = (float*)d_ws;
    uint16_t* xtb  = (uint16_t*)ws;                     // 16 MB
    uint16_t* kd4b = (uint16_t*)(ws + 4194304);         // 8 MB
    uint16_t* ytb  = (uint16_t*)(ws + 6291456);         // 16 MB
    float* w       = ws + 10485760;                     // 8 MB
    float* LAg     = ws + 4194304 + 65536;              // 16 KB  [4][1024]
    float* SBg     = ws + 4194304 + 69632;              // 8 KB   [2][1024]

    k_pre <<<2054, 256, 0, stream>>>(x, xtb, A, B1, B2, LAg, SBg);
    k_w   <<<2048, 256, 0, stream>>>(om, LAg, SBg, w);
    k_kd  <<<dim3(64, 8), 256, 0, stream>>>(w, C1, C2, kd4b);
    k_conv<<<1024, 256, 0, stream>>>(xtb, kd4b, ytb);
    k_t2  <<<dim3(32, 8, 8), 256, 0, stream>>>(ytb, x, omg, out);
}